// Round 9
// baseline (397.889 us; speedup 1.0000x reference)
//
#include <hip/hip_runtime.h>
#include <hip/hip_bf16.h>
#include <hip/hip_fp16.h>

// ---------------------------------------------------------------------------
// GCN 3-layer forward. N=100000, E=1600000, F: 64 -> 128 -> 128 -> 64.
// R9: dynamic node-stealing in fag phase-1 (kills the static-assignment
//     straggler stall that held fused agg+GEMM at 3.0 TB/s).
//   CSR: phist -> scan_blocks -> mid -> part2 -> finalize
//   F1: fag<64,128>  msgX(P) -> msg1(Q)   [+b1, relu, *dinv]
//   F2: fag<128,128> msg1(Q) -> h2(P)     [+b2, relu]
//   gemm3<128,64> h2(P) -> msg3(Q)        [*dinv]
//   agg3<64> msg3(Q) -> out (+b3, f32)
// ---------------------------------------------------------------------------

typedef _Float16 h8 __attribute__((ext_vector_type(8)));
typedef float f4 __attribute__((ext_vector_type(4)));

constexpr int BSHIFT = 7;                 // 128 nodes per bucket
constexpr int BNODES = 1 << BSHIFT;
constexpr int PB     = 256;               // partition blocks
constexpr int CAP    = 4096;              // finalize LDS stage capacity

// ---- f16 helpers ----------------------------------------------------------
__device__ inline void load8h(const _Float16* p, float* f) {
    h8 v = *(const h8*)p;
#pragma unroll
    for (int j = 0; j < 8; j++) f[j] = (float)v[j];
}

__device__ inline void store8h(_Float16* p, const float* f) {
    h8 v;
#pragma unroll
    for (int j = 0; j < 8; j++) v[j] = (_Float16)f[j];
    *(h8*)p = v;
}

__device__ inline void store4h(_Float16* p, float4 v) {
    _Float16 t[4] = {(_Float16)v.x, (_Float16)v.y, (_Float16)v.z, (_Float16)v.w};
    *(uint2*)p = *(uint2*)t;
}

// ---- CSR build ------------------------------------------------------------
__global__ __launch_bounds__(256) void phist_k(const int* __restrict__ dst,
                                               int* __restrict__ hist,
                                               int E, int nbuck, int chunk) {
    __shared__ int h[1024];
    for (int i = threadIdx.x; i < nbuck; i += 256) h[i] = 0;
    __syncthreads();
    int beg = blockIdx.x * chunk;
    int end = min(E, beg + chunk);
    for (int e = beg + threadIdx.x; e < end; e += 256)
        atomicAdd(&h[dst[e] >> BSHIFT], 1);
    __syncthreads();
    for (int i = threadIdx.x; i < nbuck; i += 256)
        hist[(long)blockIdx.x * nbuck + i] = h[i];
}

__global__ __launch_bounds__(256) void scan_blocks_k(const int* __restrict__ in,
                                                     int* __restrict__ excl,
                                                     int* __restrict__ bsums, int n) {
    __shared__ int s[256];
    int tid = threadIdx.x;
    int i = blockIdx.x * 256 + tid;
    int v = (i < n) ? in[i] : 0;
    s[tid] = v;
    __syncthreads();
    for (int off = 1; off < 256; off <<= 1) {
        int t = (tid >= off) ? s[tid - off] : 0;
        __syncthreads();
        s[tid] += t;
        __syncthreads();
    }
    if (i < n) excl[i] = s[tid] - v;
    if (tid == 255) bsums[blockIdx.x] = s[255];
}

// block 0: exclusive scan of bsums; block 1: column-sum hist -> scan -> bbase
__global__ __launch_bounds__(1024) void mid_k(int* __restrict__ bsums, int nb,
                                              const int* __restrict__ hist,
                                              int* __restrict__ bbase,
                                              int nbuck, int E) {
    __shared__ int s[1024];
    int tid = threadIdx.x;
    int v = 0;
    if (blockIdx.x == 0) {
        v = (tid < nb) ? bsums[tid] : 0;
    } else {
        if (tid < nbuck) {
            int t0 = 0, t1 = 0, t2 = 0, t3 = 0;
            for (int j = 0; j < PB; j += 4) {
                t0 += hist[(long)(j + 0) * nbuck + tid];
                t1 += hist[(long)(j + 1) * nbuck + tid];
                t2 += hist[(long)(j + 2) * nbuck + tid];
                t3 += hist[(long)(j + 3) * nbuck + tid];
            }
            v = (t0 + t1) + (t2 + t3);
        }
    }
    s[tid] = v;
    __syncthreads();
    for (int off = 1; off < 1024; off <<= 1) {
        int t = (tid >= off) ? s[tid - off] : 0;
        __syncthreads();
        s[tid] += t;
        __syncthreads();
    }
    if (blockIdx.x == 0) {
        if (tid < nb) bsums[tid] = s[tid] - v;
    } else {
        if (tid < nbuck) bbase[tid] = s[tid] - v;
        if (tid == 0) bbase[nbuck] = E;
    }
}

__global__ __launch_bounds__(256) void part2_k(const int* __restrict__ src,
                                               const int* __restrict__ dst,
                                               const int* __restrict__ offs,
                                               const int* __restrict__ bsums,
                                               unsigned* __restrict__ ebuf,
                                               int E, int nbuck, int chunk) {
    __shared__ int cur[1024];
    for (int i = threadIdx.x; i < nbuck; i += 256) {
        long flat = (long)blockIdx.x * nbuck + i;
        cur[i] = offs[flat] + bsums[flat >> 8];
    }
    __syncthreads();
    int beg = blockIdx.x * chunk;
    int end = min(E, beg + chunk);
    for (int e = beg + threadIdx.x; e < end; e += 256) {
        int d = dst[e];
        int b = d >> BSHIFT;
        int pos = atomicAdd(&cur[b], 1);
        ebuf[pos] = ((unsigned)(d & (BNODES - 1)) << 25) | (unsigned)src[e];
    }
}

__global__ __launch_bounds__(256) void finalize_k(const unsigned* __restrict__ ebuf,
                                                  const int* __restrict__ hist,
                                                  const int* __restrict__ offs,
                                                  const int* __restrict__ bsums,
                                                  const int* __restrict__ bbase,
                                                  int nbuck,
                                                  int* __restrict__ rowst,
                                                  int* __restrict__ rowend,
                                                  float* __restrict__ dinv,
                                                  int* __restrict__ col,
                                                  const float* __restrict__ x,
                                                  _Float16* __restrict__ msgX, int N) {
    __shared__ unsigned se[CAP];
    __shared__ int cj[PB], sj[PB], sb[PB];
    __shared__ int cnt_s[BNODES], scan_s[BNODES], cur_s[BNODES];
    __shared__ float di_s[BNODES];

    int b = blockIdx.x, tid = threadIdx.x;
    int node0 = b << BSHIFT;
    int nn = min(BNODES, N - node0);
    int beg = bbase[b];

    if (tid < PB) {
        long flat = (long)tid * nbuck + b;
        cj[tid] = hist[flat];
        sj[tid] = offs[flat] + bsums[flat >> 8];
    }
    if (tid < BNODES) cnt_s[tid] = 0;
    __syncthreads();

    if (tid < PB) sb[tid] = cj[tid];
    __syncthreads();
    for (int off = 1; off < PB; off <<= 1) {
        int t = 0;
        if (tid < PB && tid >= off) t = sb[tid - off];
        __syncthreads();
        if (tid < PB) sb[tid] += t;
        __syncthreads();
    }
    int m = sb[PB - 1];
    __syncthreads();

    // gather segments into LDS: 1 thread per segment (~8 edges each)
    {
        int j = tid;
        int base = sb[j] - cj[j], c = cj[j], s0 = sj[j];
        for (int k = 0; k < c; k++) {
            unsigned e = ebuf[s0 + k];
            int idx = base + k;
            if (idx < CAP) se[idx] = e;
            else atomicAdd(&cnt_s[e >> 25], 1);
        }
    }
    __syncthreads();

    int mcap = m < CAP ? m : CAP;
    for (int i = tid; i < mcap; i += 256) atomicAdd(&cnt_s[se[i] >> 25], 1);
    __syncthreads();

    int v = (tid < BNODES) ? cnt_s[tid] : 0;
    if (tid < BNODES) scan_s[tid] = v;
    __syncthreads();
    for (int off = 1; off < BNODES; off <<= 1) {
        int t = 0;
        if (tid < BNODES && tid >= off) t = scan_s[tid - off];
        __syncthreads();
        if (tid < BNODES) scan_s[tid] += t;
        __syncthreads();
    }
    if (tid < nn) {
        int ex = scan_s[tid] - v;
        int st = beg + ex;
        rowst[node0 + tid] = st;
        rowend[node0 + tid] = st + v;
        float di = rsqrtf((float)v + 1.0f);
        dinv[node0 + tid] = di;
        di_s[tid] = di;
        cur_s[tid] = ex;
    }
    __syncthreads();

    for (int i = tid; i < mcap; i += 256) {
        unsigned e = se[i];
        int p = atomicAdd(&cur_s[e >> 25], 1);
        col[beg + p] = (int)(e & 0x1FFFFFFu);
    }
    if (m > CAP) {  // overflow spill (statistically never)
        int j = tid;
        int base = sb[j] - cj[j], c = cj[j], s0 = sj[j];
        for (int k = 0; k < c; k++) {
            int idx = base + k;
            if (idx >= CAP) {
                unsigned e = ebuf[s0 + k];
                int p = atomicAdd(&cur_s[e >> 25], 1);
                col[beg + p] = (int)(e & 0x1FFFFFFu);
            }
        }
    }

    // fused msgX prep: msgX[n,64] f16 = dinv[n] * x[n,:]
    for (int t = tid; t < nn * 16; t += 256) {
        int nl = t >> 4, q = t & 15;
        int node = node0 + nl;
        float4 vx = *(const float4*)(x + (long)node * 64 + q * 4);
        float di = di_s[nl];
        vx.x *= di; vx.y *= di; vx.z *= di; vx.w *= di;
        store4h(msgX + (long)node * 64 + q * 4, vx);
    }
}

// ---- fused aggregate + MFMA GEMM ------------------------------------------
// block = 64 nodes. Phase 1: DYNAMIC node-stealing gather into LDS tile.
// Phase 2: C[64,FOUT] = epi(As @ W), W B-fragments from global (L1/L2-hot).
template <int K, int FOUT, bool BIAS, bool RELU, bool DINV_OUT>
__global__ __launch_bounds__(256) void fag_k(const _Float16* __restrict__ msg,
                                             const int* __restrict__ rowst,
                                             const int* __restrict__ rowend,
                                             const int* __restrict__ col,
                                             const float* __restrict__ dinv,
                                             const _Float16* __restrict__ Wsw,
                                             const float* __restrict__ bias,
                                             _Float16* __restrict__ C, int n) {
    constexpr int NT = FOUT / 16, NC = K / 32;
    constexpr int LDK = K + 8;          // pad: phase-2 LDS reads 2-way only
    constexpr int LPN = K / 8;          // lanes per node
    __shared__ _Float16 As[64 * LDK];
    __shared__ int next_s;

    int tid = threadIdx.x;
    int row0 = blockIdx.x * 64;
    if (tid == 0) next_s = 0;
    __syncthreads();

    // phase 1: dynamic stealing — each LPN-lane group grabs the next node
    int lane = tid & 63;
    int q = tid % LPN;
    int gbase = lane & ~(LPN - 1);      // group's first lane within wave
    for (;;) {
        int idx;
        if (q == 0) idx = atomicAdd(&next_s, 1);
        idx = __shfl(idx, gbase);
        if (idx >= 64) break;
        int node = row0 + idx;
        float acc[8];
        if (node < n) {
            load8h(msg + (long)node * K + q * 8, acc);  // self (dinv folded)
            int beg = rowst[node], end = rowend[node];
            int e = beg;
            for (; e + 4 <= end; e += 4) {
                int s0 = col[e], s1 = col[e + 1], s2 = col[e + 2], s3 = col[e + 3];
                float v0[8], v1[8], v2[8], v3[8];
                load8h(msg + (long)s0 * K + q * 8, v0);
                load8h(msg + (long)s1 * K + q * 8, v1);
                load8h(msg + (long)s2 * K + q * 8, v2);
                load8h(msg + (long)s3 * K + q * 8, v3);
#pragma unroll
                for (int j = 0; j < 8; j++) acc[j] += (v0[j] + v1[j]) + (v2[j] + v3[j]);
            }
            for (; e < end; e++) {
                int s = col[e];
                float v[8];
                load8h(msg + (long)s * K + q * 8, v);
#pragma unroll
                for (int j = 0; j < 8; j++) acc[j] += v[j];
            }
            float di = dinv[node];
#pragma unroll
            for (int j = 0; j < 8; j++) acc[j] *= di;
        } else {
#pragma unroll
            for (int j = 0; j < 8; j++) acc[j] = 0.f;
        }
        h8 o;
#pragma unroll
        for (int j = 0; j < 8; j++) o[j] = (_Float16)acc[j];
        *(h8*)(As + idx * LDK + q * 8) = o;
    }
    __syncthreads();

    // phase 2: MFMA, one 16-row tile per wave
    int wave = tid >> 6;
    int quad = lane >> 4, cl = lane & 15;
    int r0 = wave * 16;

    h8 a[NC];
#pragma unroll
    for (int c = 0; c < NC; c++)
        a[c] = *(const h8*)(As + (r0 + cl) * LDK + quad * 8 + c * 32);

    f4 acc2[NT];
#pragma unroll
    for (int t = 0; t < NT; t++) acc2[t] = (f4){0.f, 0.f, 0.f, 0.f};

    const h8* wv = (const h8*)Wsw;
#pragma unroll
    for (int c = 0; c < NC; c++) {
#pragma unroll
        for (int t = 0; t < NT; t++)
            acc2[t] = __builtin_amdgcn_mfma_f32_16x16x32_f16(
                a[c], wv[(c * NT + t) * 64 + lane], acc2[t], 0, 0, 0);
    }

    // C/D layout: col = lane&15, row = quad*4 + reg
#pragma unroll
    for (int t = 0; t < NT; t++) {
        int c0 = t * 16 + cl;
        float bb = BIAS ? bias[c0] : 0.f;
#pragma unroll
        for (int r = 0; r < 4; r++) {
            int row = row0 + r0 + quad * 4 + r;
            if (row >= n) continue;
            float v = acc2[t][r] + bb;
            if (RELU) v = fmaxf(v, 0.f);
            if (DINV_OUT) v *= dinv[row];
            C[(long)row * FOUT + c0] = (_Float16)v;
        }
    }
}

// ---- standalone aggregation (layer 3 output) ------------------------------
template <int F, bool BIAS, bool F16OUT>
__global__ __launch_bounds__(256) void agg_f16_k(const _Float16* __restrict__ msg,
                                                 const int* __restrict__ rowst,
                                                 const int* __restrict__ rowend,
                                                 const int* __restrict__ col,
                                                 const float* __restrict__ dinv,
                                                 const float* __restrict__ b,
                                                 void* __restrict__ out, int n) {
    constexpr int LPN = F / 8;
    constexpr int NPB = 256 / LPN;
    int node = blockIdx.x * NPB + threadIdx.x / LPN;
    int q = threadIdx.x % LPN;
    if (node >= n) return;

    float acc[8];
    load8h(msg + (long)node * F + q * 8, acc);

    int beg = rowst[node], end = rowend[node];
    int e = beg;
    for (; e + 4 <= end; e += 4) {
        int s0 = col[e], s1 = col[e + 1], s2 = col[e + 2], s3 = col[e + 3];
        float v0[8], v1[8], v2[8], v3[8];
        load8h(msg + (long)s0 * F + q * 8, v0);
        load8h(msg + (long)s1 * F + q * 8, v1);
        load8h(msg + (long)s2 * F + q * 8, v2);
        load8h(msg + (long)s3 * F + q * 8, v3);
#pragma unroll
        for (int j = 0; j < 8; j++) acc[j] += (v0[j] + v1[j]) + (v2[j] + v3[j]);
    }
    for (; e < end; e++) {
        int s = col[e];
        float v[8];
        load8h(msg + (long)s * F + q * 8, v);
#pragma unroll
        for (int j = 0; j < 8; j++) acc[j] += v[j];
    }

    float di = dinv[node];
    float o[8];
#pragma unroll
    for (int j = 0; j < 8; j++) o[j] = di * acc[j];
    if (BIAS) {
#pragma unroll
        for (int j = 0; j < 8; j++) o[j] += b[q * 8 + j];
    }
    if (F16OUT) {
        store8h((_Float16*)out + (long)node * F + q * 8, o);
    } else {
        float* dst = (float*)out + (long)node * F + q * 8;
        *(float4*)dst = make_float4(o[0], o[1], o[2], o[3]);
        *(float4*)(dst + 4) = make_float4(o[4], o[5], o[6], o[7]);
    }
}

// ---- weight swizzle + layer-3 GEMM ----------------------------------------
template <int K, int FOUT>
__device__ inline void wfrag(const float* __restrict__ W,
                             _Float16* __restrict__ Wsw, int t) {
    constexpr int NT = FOUT / 16;
    int lane = t & 63;
    int tile = (t >> 6) % NT;
    int chunk = (t >> 6) / NT;
    int kbase = chunk * 32 + (lane >> 4) * 8;
    int nc = tile * 16 + (lane & 15);
    h8 v;
#pragma unroll
    for (int j = 0; j < 8; j++) v[j] = (_Float16)W[(kbase + j) * FOUT + nc];
    ((h8*)Wsw)[t] = v;
}

__global__ __launch_bounds__(256) void wprep3_k(const float* __restrict__ W1,
                                                const float* __restrict__ W2,
                                                const float* __restrict__ W3,
                                                _Float16* __restrict__ w1s,
                                                _Float16* __restrict__ w2s,
                                                _Float16* __restrict__ w3s) {
    int t = blockIdx.x * 256 + threadIdx.x;
    if (t < 1024) wfrag<64, 128>(W1, w1s, t);
    else if (t < 3072) wfrag<128, 128>(W2, w2s, t - 1024);
    else if (t < 4096) wfrag<128, 64>(W3, w3s, t - 3072);
}

template <int K, int FOUT, bool BIAS, bool RELU, bool DINV>
__global__ __launch_bounds__(256) void gemm_mfma_k(const _Float16* __restrict__ A,
                                                   const _Float16* __restrict__ Wsw,
                                                   const float* __restrict__ bias,
                                                   const float* __restrict__ dinv,
                                                   _Float16* __restrict__ C, int n) {
    constexpr int NT = FOUT / 16;
    constexpr int NC = K / 32;
    __shared__ _Float16 wl[K * FOUT];

    int tid = threadIdx.x;
    for (int i = tid; i < K * FOUT / 8; i += 256)
        ((h8*)wl)[i] = ((const h8*)Wsw)[i];
    __syncthreads();

    int lane = tid & 63, wave = tid >> 6;
    int quad = lane >> 4, cl = lane & 15;
    int row0 = blockIdx.x * 64 + wave * 16;

    h8 a[NC];
    const _Float16* arow = A + (long)(row0 + cl) * K + quad * 8;
#pragma unroll
    for (int c = 0; c < NC; c++) a[c] = *(const h8*)(arow + c * 32);

    f4 acc[NT];
#pragma unroll
    for (int t = 0; t < NT; t++) acc[t] = (f4){0.f, 0.f, 0.f, 0.f};

    const h8* wv = (const h8*)wl;
#pragma unroll
    for (int c = 0; c < NC; c++) {
#pragma unroll
        for (int t = 0; t < NT; t++)
            acc[t] = __builtin_amdgcn_mfma_f32_16x16x32_f16(
                a[c], wv[(c * NT + t) * 64 + lane], acc[t], 0, 0, 0);
    }

#pragma unroll
    for (int t = 0; t < NT; t++) {
        int c0 = t * 16 + cl;
        float bb = BIAS ? bias[c0] : 0.f;
#pragma unroll
        for (int r = 0; r < 4; r++) {
            int row = row0 + quad * 4 + r;
            if (row >= n) continue;
            float v = acc[t][r] + bb;
            if (RELU) v = fmaxf(v, 0.f);
            if (DINV) v *= dinv[row];
            C[(long)row * FOUT + c0] = (_Float16)v;
        }
    }
}

extern "C" void kernel_launch(void* const* d_in, const int* in_sizes, int n_in,
                              void* d_out, int out_size, void* d_ws, size_t ws_size,
                              hipStream_t stream) {
    const float* x  = (const float*)d_in[0];
    const int*   ei = (const int*)d_in[1];
    const float* W1 = (const float*)d_in[2];
    const float* b1 = (const float*)d_in[3];
    const float* W2 = (const float*)d_in[4];
    const float* b2 = (const float*)d_in[5];
    const float* W3 = (const float*)d_in[6];
    const float* b3 = (const float*)d_in[7];
    float* out = (float*)d_out;

    const int N = in_sizes[0] / 64;
    const int E = in_sizes[1] / 2;
    const int* src = ei;
    const int* dst = ei + E;
    const int nbuck = (N + BNODES - 1) >> BSHIFT;   // 782
    const int chunk = (E + PB - 1) / PB;            // 6250
    const int n2 = PB * nbuck;                      // 200192
    const int nb2 = (n2 + 255) / 256;               // 782

    // workspace carve-up (4-byte elems)
    int*   hist   = (int*)d_ws;                   // PB*nbuck
    int*   offs   = hist + n2;                    // PB*nbuck
    int*   bsums  = offs + n2;                    // 1024
    int*   bbase  = bsums + 1024;                 // nbuck+1
    int*   rowst  = bbase + nbuck + 1;            // N
    int*   rowend = rowst + N;                    // N
    float* dinv   = (float*)(rowend + N);         // N
    int*   col    = (int*)(dinv + N);             // E
    _Float16* w1s = (_Float16*)(col + E);         // 64*128 f16
    _Float16* w2s = w1s + 64 * 128;               // 128*128 f16
    _Float16* w3s = w2s + 128 * 128;              // 128*64 f16
    float* P      = (float*)(w3s + 128 * 64);     // N*128 f32 worth
    float* Q      = P + (long)N * 128;            // N*128 f32 worth

    _Float16* msgX = (_Float16*)P;    // N x 64 f16
    unsigned* ebuf = (unsigned*)Q;    // E x 4B (dead after finalize)
    _Float16* msg1 = (_Float16*)Q;    // N x 128 f16
    _Float16* h2   = (_Float16*)P;    // N x 128 f16 (msgX dead)
    _Float16* msg3 = (_Float16*)Q;    // N x 64 f16  (msg1 dead)

    const int gb = (N + 63) / 64;

    // ---- weight swizzle ----
    wprep3_k<<<16, 256, 0, stream>>>(W1, W2, W3, w1s, w2s, w3s);

    // ---- CSR build ----
    phist_k<<<PB, 256, 0, stream>>>(dst, hist, E, nbuck, chunk);
    scan_blocks_k<<<nb2, 256, 0, stream>>>(hist, offs, bsums, n2);
    mid_k<<<2, 1024, 0, stream>>>(bsums, nb2, hist, bbase, nbuck, E);
    part2_k<<<PB, 256, 0, stream>>>(src, dst, offs, bsums, ebuf, E, nbuck, chunk);
    finalize_k<<<nbuck, 256, 0, stream>>>(ebuf, hist, offs, bsums, bbase, nbuck,
                                          rowst, rowend, dinv, col, x, msgX, N);

    // ---- layer 1 (fused agg+gemm): msgX(P) -> msg1(Q) ----
    fag_k<64, 128, true, true, true><<<gb, 256, 0, stream>>>(
        msgX, rowst, rowend, col, dinv, w1s, b1, msg1, N);

    // ---- layer 2 (fused agg+gemm): msg1(Q) -> h2(P) ----
    fag_k<128, 128, true, true, false><<<gb, 256, 0, stream>>>(
        msg1, rowst, rowend, col, dinv, w2s, b2, h2, N);

    // ---- layer 3: gemm h2(P) -> msg3(Q); agg -> out ----
    gemm_mfma_k<128, 64, false, false, true><<<gb, 256, 0, stream>>>(
        h2, w3s, nullptr, dinv, msg3, N);
    agg_f16_k<64, true, false><<<(N + 31) / 32, 256, 0, stream>>>(
        msg3, rowst, rowend, col, dinv, b3, (void*)out, N);
}

// Round 10
// 383.239 us; speedup vs baseline: 1.0382x; 1.0382x over previous
//
#include <hip/hip_runtime.h>
#include <hip/hip_bf16.h>
#include <hip/hip_fp16.h>

// ---------------------------------------------------------------------------
// GCN 3-layer forward. N=100000, E=1600000, F: 64 -> 128 -> 128 -> 64.
// R10: layer-2 gather un-fused (standalone agg won: 83 vs 101.5 us fused);
//      gemm2+gemm3 fused into one double-GEMM (h2 tile stays in LDS);
//      gather unroll 4 -> 8.
//   CSR: phist -> scan_blocks -> mid -> part2 -> finalize
//   F1: fag<64,128>  msgX(P) -> msg1(Q)      [+b1, relu, *dinv]
//   agg2<128> msg1(Q) -> aggH1(P)            [*dinv, f16]
//   dgemm: aggH1(P) -> msg3(Q)               [W2,+b2,relu | W3,*dinv]
//   agg3<64> msg3(Q) -> out (+b3, f32)
// ---------------------------------------------------------------------------

typedef _Float16 h8 __attribute__((ext_vector_type(8)));
typedef float f4 __attribute__((ext_vector_type(4)));

constexpr int BSHIFT = 7;                 // 128 nodes per bucket
constexpr int BNODES = 1 << BSHIFT;
constexpr int PB     = 256;               // partition blocks
constexpr int CAP    = 4096;              // finalize LDS stage capacity

// ---- f16 helpers ----------------------------------------------------------
__device__ inline void load8h(const _Float16* p, float* f) {
    h8 v = *(const h8*)p;
#pragma unroll
    for (int j = 0; j < 8; j++) f[j] = (float)v[j];
}

__device__ inline void store8h(_Float16* p, const float* f) {
    h8 v;
#pragma unroll
    for (int j = 0; j < 8; j++) v[j] = (_Float16)f[j];
    *(h8*)p = v;
}

__device__ inline void store4h(_Float16* p, float4 v) {
    _Float16 t[4] = {(_Float16)v.x, (_Float16)v.y, (_Float16)v.z, (_Float16)v.w};
    *(uint2*)p = *(uint2*)t;
}

// ---- CSR build ------------------------------------------------------------
__global__ __launch_bounds__(256) void phist_k(const int* __restrict__ dst,
                                               int* __restrict__ hist,
                                               int E, int nbuck, int chunk) {
    __shared__ int h[1024];
    for (int i = threadIdx.x; i < nbuck; i += 256) h[i] = 0;
    __syncthreads();
    int beg = blockIdx.x * chunk;
    int end = min(E, beg + chunk);
    for (int e = beg + threadIdx.x; e < end; e += 256)
        atomicAdd(&h[dst[e] >> BSHIFT], 1);
    __syncthreads();
    for (int i = threadIdx.x; i < nbuck; i += 256)
        hist[(long)blockIdx.x * nbuck + i] = h[i];
}

__global__ __launch_bounds__(256) void scan_blocks_k(const int* __restrict__ in,
                                                     int* __restrict__ excl,
                                                     int* __restrict__ bsums, int n) {
    __shared__ int s[256];
    int tid = threadIdx.x;
    int i = blockIdx.x * 256 + tid;
    int v = (i < n) ? in[i] : 0;
    s[tid] = v;
    __syncthreads();
    for (int off = 1; off < 256; off <<= 1) {
        int t = (tid >= off) ? s[tid - off] : 0;
        __syncthreads();
        s[tid] += t;
        __syncthreads();
    }
    if (i < n) excl[i] = s[tid] - v;
    if (tid == 255) bsums[blockIdx.x] = s[255];
}

// block 0: exclusive scan of bsums; block 1: column-sum hist -> scan -> bbase
__global__ __launch_bounds__(1024) void mid_k(int* __restrict__ bsums, int nb,
                                              const int* __restrict__ hist,
                                              int* __restrict__ bbase,
                                              int nbuck, int E) {
    __shared__ int s[1024];
    int tid = threadIdx.x;
    int v = 0;
    if (blockIdx.x == 0) {
        v = (tid < nb) ? bsums[tid] : 0;
    } else {
        if (tid < nbuck) {
            int t0 = 0, t1 = 0, t2 = 0, t3 = 0;
            for (int j = 0; j < PB; j += 4) {
                t0 += hist[(long)(j + 0) * nbuck + tid];
                t1 += hist[(long)(j + 1) * nbuck + tid];
                t2 += hist[(long)(j + 2) * nbuck + tid];
                t3 += hist[(long)(j + 3) * nbuck + tid];
            }
            v = (t0 + t1) + (t2 + t3);
        }
    }
    s[tid] = v;
    __syncthreads();
    for (int off = 1; off < 1024; off <<= 1) {
        int t = (tid >= off) ? s[tid - off] : 0;
        __syncthreads();
        s[tid] += t;
        __syncthreads();
    }
    if (blockIdx.x == 0) {
        if (tid < nb) bsums[tid] = s[tid] - v;
    } else {
        if (tid < nbuck) bbase[tid] = s[tid] - v;
        if (tid == 0) bbase[nbuck] = E;
    }
}

__global__ __launch_bounds__(256) void part2_k(const int* __restrict__ src,
                                               const int* __restrict__ dst,
                                               const int* __restrict__ offs,
                                               const int* __restrict__ bsums,
                                               unsigned* __restrict__ ebuf,
                                               int E, int nbuck, int chunk) {
    __shared__ int cur[1024];
    for (int i = threadIdx.x; i < nbuck; i += 256) {
        long flat = (long)blockIdx.x * nbuck + i;
        cur[i] = offs[flat] + bsums[flat >> 8];
    }
    __syncthreads();
    int beg = blockIdx.x * chunk;
    int end = min(E, beg + chunk);
    for (int e = beg + threadIdx.x; e < end; e += 256) {
        int d = dst[e];
        int b = d >> BSHIFT;
        int pos = atomicAdd(&cur[b], 1);
        ebuf[pos] = ((unsigned)(d & (BNODES - 1)) << 25) | (unsigned)src[e];
    }
}

__global__ __launch_bounds__(256) void finalize_k(const unsigned* __restrict__ ebuf,
                                                  const int* __restrict__ hist,
                                                  const int* __restrict__ offs,
                                                  const int* __restrict__ bsums,
                                                  const int* __restrict__ bbase,
                                                  int nbuck,
                                                  int* __restrict__ rowst,
                                                  int* __restrict__ rowend,
                                                  float* __restrict__ dinv,
                                                  int* __restrict__ col,
                                                  const float* __restrict__ x,
                                                  _Float16* __restrict__ msgX, int N) {
    __shared__ unsigned se[CAP];
    __shared__ int cj[PB], sj[PB], sb[PB];
    __shared__ int cnt_s[BNODES], scan_s[BNODES], cur_s[BNODES];
    __shared__ float di_s[BNODES];

    int b = blockIdx.x, tid = threadIdx.x;
    int node0 = b << BSHIFT;
    int nn = min(BNODES, N - node0);
    int beg = bbase[b];

    if (tid < PB) {
        long flat = (long)tid * nbuck + b;
        cj[tid] = hist[flat];
        sj[tid] = offs[flat] + bsums[flat >> 8];
    }
    if (tid < BNODES) cnt_s[tid] = 0;
    __syncthreads();

    if (tid < PB) sb[tid] = cj[tid];
    __syncthreads();
    for (int off = 1; off < PB; off <<= 1) {
        int t = 0;
        if (tid < PB && tid >= off) t = sb[tid - off];
        __syncthreads();
        if (tid < PB) sb[tid] += t;
        __syncthreads();
    }
    int m = sb[PB - 1];
    __syncthreads();

    // gather segments into LDS: 1 thread per segment (~8 edges each)
    {
        int j = tid;
        int base = sb[j] - cj[j], c = cj[j], s0 = sj[j];
        for (int k = 0; k < c; k++) {
            unsigned e = ebuf[s0 + k];
            int idx = base + k;
            if (idx < CAP) se[idx] = e;
            else atomicAdd(&cnt_s[e >> 25], 1);
        }
    }
    __syncthreads();

    int mcap = m < CAP ? m : CAP;
    for (int i = tid; i < mcap; i += 256) atomicAdd(&cnt_s[se[i] >> 25], 1);
    __syncthreads();

    int v = (tid < BNODES) ? cnt_s[tid] : 0;
    if (tid < BNODES) scan_s[tid] = v;
    __syncthreads();
    for (int off = 1; off < BNODES; off <<= 1) {
        int t = 0;
        if (tid < BNODES && tid >= off) t = scan_s[tid - off];
        __syncthreads();
        if (tid < BNODES) scan_s[tid] += t;
        __syncthreads();
    }
    if (tid < nn) {
        int ex = scan_s[tid] - v;
        int st = beg + ex;
        rowst[node0 + tid] = st;
        rowend[node0 + tid] = st + v;
        float di = rsqrtf((float)v + 1.0f);
        dinv[node0 + tid] = di;
        di_s[tid] = di;
        cur_s[tid] = ex;
    }
    __syncthreads();

    for (int i = tid; i < mcap; i += 256) {
        unsigned e = se[i];
        int p = atomicAdd(&cur_s[e >> 25], 1);
        col[beg + p] = (int)(e & 0x1FFFFFFu);
    }
    if (m > CAP) {  // overflow spill (statistically never)
        int j = tid;
        int base = sb[j] - cj[j], c = cj[j], s0 = sj[j];
        for (int k = 0; k < c; k++) {
            int idx = base + k;
            if (idx >= CAP) {
                unsigned e = ebuf[s0 + k];
                int p = atomicAdd(&cur_s[e >> 25], 1);
                col[beg + p] = (int)(e & 0x1FFFFFFu);
            }
        }
    }

    // fused msgX prep: msgX[n,64] f16 = dinv[n] * x[n,:]
    for (int t = tid; t < nn * 16; t += 256) {
        int nl = t >> 4, q = t & 15;
        int node = node0 + nl;
        float4 vx = *(const float4*)(x + (long)node * 64 + q * 4);
        float di = di_s[nl];
        vx.x *= di; vx.y *= di; vx.z *= di; vx.w *= di;
        store4h(msgX + (long)node * 64 + q * 4, vx);
    }
}

// ---- fused aggregate + MFMA GEMM (layer 1 only, K=64) ---------------------
template <int K, int FOUT, bool BIAS, bool RELU, bool DINV_OUT>
__global__ __launch_bounds__(256) void fag_k(const _Float16* __restrict__ msg,
                                             const int* __restrict__ rowst,
                                             const int* __restrict__ rowend,
                                             const int* __restrict__ col,
                                             const float* __restrict__ dinv,
                                             const _Float16* __restrict__ Wsw,
                                             const float* __restrict__ bias,
                                             _Float16* __restrict__ C, int n) {
    constexpr int NT = FOUT / 16, NC = K / 32;
    constexpr int LDK = K + 8;
    constexpr int LPN = K / 8;
    constexpr int NPB = 256 / LPN;
    __shared__ _Float16 As[64 * LDK];

    int tid = threadIdx.x;
    int row0 = blockIdx.x * 64;

#pragma unroll
    for (int pass = 0; pass < 64 / NPB; pass++) {
        int nl = pass * NPB + tid / LPN;
        int q = tid % LPN;
        int node = row0 + nl;
        float acc[8];
        if (node < n) {
            load8h(msg + (long)node * K + q * 8, acc);  // self (dinv folded)
            int beg = rowst[node], end = rowend[node];
            int e = beg;
            for (; e + 4 <= end; e += 4) {
                int s0 = col[e], s1 = col[e + 1], s2 = col[e + 2], s3 = col[e + 3];
                h8 v0 = *(const h8*)(msg + (long)s0 * K + q * 8);
                h8 v1 = *(const h8*)(msg + (long)s1 * K + q * 8);
                h8 v2 = *(const h8*)(msg + (long)s2 * K + q * 8);
                h8 v3 = *(const h8*)(msg + (long)s3 * K + q * 8);
#pragma unroll
                for (int j = 0; j < 8; j++)
                    acc[j] += ((float)v0[j] + (float)v1[j]) + ((float)v2[j] + (float)v3[j]);
            }
            for (; e < end; e++) {
                int s = col[e];
                h8 v = *(const h8*)(msg + (long)s * K + q * 8);
#pragma unroll
                for (int j = 0; j < 8; j++) acc[j] += (float)v[j];
            }
            float di = dinv[node];
#pragma unroll
            for (int j = 0; j < 8; j++) acc[j] *= di;
        } else {
#pragma unroll
            for (int j = 0; j < 8; j++) acc[j] = 0.f;
        }
        h8 o;
#pragma unroll
        for (int j = 0; j < 8; j++) o[j] = (_Float16)acc[j];
        *(h8*)(As + nl * LDK + q * 8) = o;
    }
    __syncthreads();

    int lane = tid & 63, wave = tid >> 6;
    int quad = lane >> 4, cl = lane & 15;
    int r0 = wave * 16;

    h8 a[NC];
#pragma unroll
    for (int c = 0; c < NC; c++)
        a[c] = *(const h8*)(As + (r0 + cl) * LDK + quad * 8 + c * 32);

    f4 acc2[NT];
#pragma unroll
    for (int t = 0; t < NT; t++) acc2[t] = (f4){0.f, 0.f, 0.f, 0.f};

    const h8* wv = (const h8*)Wsw;
#pragma unroll
    for (int c = 0; c < NC; c++) {
#pragma unroll
        for (int t = 0; t < NT; t++)
            acc2[t] = __builtin_amdgcn_mfma_f32_16x16x32_f16(
                a[c], wv[(c * NT + t) * 64 + lane], acc2[t], 0, 0, 0);
    }

#pragma unroll
    for (int t = 0; t < NT; t++) {
        int c0 = t * 16 + cl;
        float bb = BIAS ? bias[c0] : 0.f;
#pragma unroll
        for (int r = 0; r < 4; r++) {
            int row = row0 + r0 + quad * 4 + r;
            if (row >= n) continue;
            float v = acc2[t][r] + bb;
            if (RELU) v = fmaxf(v, 0.f);
            if (DINV_OUT) v *= dinv[row];
            C[(long)row * FOUT + c0] = (_Float16)v;
        }
    }
}

// ---- standalone aggregation (8x unrolled gather) --------------------------
template <int F, bool BIAS, bool F16OUT>
__global__ __launch_bounds__(256) void agg_f16_k(const _Float16* __restrict__ msg,
                                                 const int* __restrict__ rowst,
                                                 const int* __restrict__ rowend,
                                                 const int* __restrict__ col,
                                                 const float* __restrict__ dinv,
                                                 const float* __restrict__ b,
                                                 void* __restrict__ out, int n) {
    constexpr int LPN = F / 8;
    constexpr int NPB = 256 / LPN;
    int node = blockIdx.x * NPB + threadIdx.x / LPN;
    int q = threadIdx.x % LPN;
    if (node >= n) return;

    float acc[8];
    load8h(msg + (long)node * F + q * 8, acc);

    int beg = rowst[node], end = rowend[node];
    int e = beg;
    for (; e + 8 <= end; e += 8) {     // 8 independent gathers in flight
        h8 v[8];
#pragma unroll
        for (int u = 0; u < 8; u++)
            v[u] = *(const h8*)(msg + (long)col[e + u] * F + q * 8);
#pragma unroll
        for (int j = 0; j < 8; j++)
            acc[j] += (((float)v[0][j] + (float)v[1][j]) + ((float)v[2][j] + (float)v[3][j])) +
                      (((float)v[4][j] + (float)v[5][j]) + ((float)v[6][j] + (float)v[7][j]));
    }
    for (; e + 4 <= end; e += 4) {
        h8 v0 = *(const h8*)(msg + (long)col[e] * F + q * 8);
        h8 v1 = *(const h8*)(msg + (long)col[e + 1] * F + q * 8);
        h8 v2 = *(const h8*)(msg + (long)col[e + 2] * F + q * 8);
        h8 v3 = *(const h8*)(msg + (long)col[e + 3] * F + q * 8);
#pragma unroll
        for (int j = 0; j < 8; j++)
            acc[j] += ((float)v0[j] + (float)v1[j]) + ((float)v2[j] + (float)v3[j]);
    }
    for (; e < end; e++) {
        h8 v = *(const h8*)(msg + (long)col[e] * F + q * 8);
#pragma unroll
        for (int j = 0; j < 8; j++) acc[j] += (float)v[j];
    }

    float di = dinv[node];
    float o[8];
#pragma unroll
    for (int j = 0; j < 8; j++) o[j] = di * acc[j];
    if (BIAS) {
#pragma unroll
        for (int j = 0; j < 8; j++) o[j] += b[q * 8 + j];
    }
    if (F16OUT) {
        store8h((_Float16*)out + (long)node * F + q * 8, o);
    } else {
        float* dst = (float*)out + (long)node * F + q * 8;
        *(float4*)dst = make_float4(o[0], o[1], o[2], o[3]);
        *(float4*)(dst + 4) = make_float4(o[4], o[5], o[6], o[7]);
    }
}

// ---- weight swizzle -------------------------------------------------------
template <int K, int FOUT>
__device__ inline void wfrag(const float* __restrict__ W,
                             _Float16* __restrict__ Wsw, int t) {
    constexpr int NT = FOUT / 16;
    int lane = t & 63;
    int tile = (t >> 6) % NT;
    int chunk = (t >> 6) / NT;
    int kbase = chunk * 32 + (lane >> 4) * 8;
    int nc = tile * 16 + (lane & 15);
    h8 v;
#pragma unroll
    for (int j = 0; j < 8; j++) v[j] = (_Float16)W[(kbase + j) * FOUT + nc];
    ((h8*)Wsw)[t] = v;
}

__global__ __launch_bounds__(256) void wprep3_k(const float* __restrict__ W1,
                                                const float* __restrict__ W2,
                                                const float* __restrict__ W3,
                                                _Float16* __restrict__ w1s,
                                                _Float16* __restrict__ w2s,
                                                _Float16* __restrict__ w3s) {
    int t = blockIdx.x * 256 + threadIdx.x;
    if (t < 1024) wfrag<64, 128>(W1, w1s, t);
    else if (t < 3072) wfrag<128, 128>(W2, w2s, t - 1024);
    else if (t < 4096) wfrag<128, 64>(W3, w3s, t - 3072);
}

// ---- fused double GEMM: msg3 = dinv (.) ( relu(A@W2 + b2) @ W3 ) ----------
// 64 rows/block, 4 waves; each wave owns 16 rows end-to-end (no barrier:
// the intermediate tile rows are wave-private in LDS).
__global__ __launch_bounds__(256) void dgemm_k(const _Float16* __restrict__ A,
                                               const _Float16* __restrict__ w2s,
                                               const _Float16* __restrict__ w3s,
                                               const float* __restrict__ b2,
                                               const float* __restrict__ dinv,
                                               _Float16* __restrict__ C, int n) {
    constexpr int LDK = 136;
    __shared__ _Float16 Hs[64 * LDK];

    int tid = threadIdx.x, lane = tid & 63, wave = tid >> 6;
    int quad = lane >> 4, cl = lane & 15;
    int row0 = blockIdx.x * 64, r0 = wave * 16;

    // GEMM-1: rows r0..r0+15, K=128 -> 128
    h8 a[4];
    const _Float16* arow = A + (long)(row0 + r0 + cl) * 128 + quad * 8;
#pragma unroll
    for (int c = 0; c < 4; c++) a[c] = *(const h8*)(arow + c * 32);

    f4 acc1[8];
#pragma unroll
    for (int t = 0; t < 8; t++) acc1[t] = (f4){0.f, 0.f, 0.f, 0.f};
    const h8* wv2 = (const h8*)w2s;
#pragma unroll
    for (int c = 0; c < 4; c++) {
#pragma unroll
        for (int t = 0; t < 8; t++)
            acc1[t] = __builtin_amdgcn_mfma_f32_16x16x32_f16(
                a[c], wv2[(c * 8 + t) * 64 + lane], acc1[t], 0, 0, 0);
    }

    // epilogue 1: +b2, relu -> wave-private LDS rows
#pragma unroll
    for (int t = 0; t < 8; t++) {
        int c0 = t * 16 + cl;
        float bb = b2[c0];
#pragma unroll
        for (int r = 0; r < 4; r++) {
            float v = fmaxf(acc1[t][r] + bb, 0.f);
            Hs[(r0 + quad * 4 + r) * LDK + c0] = (_Float16)v;
        }
    }
    __builtin_amdgcn_s_waitcnt(0);   // drain LDS writes (wave-private rows)

    // GEMM-2: K=128 -> 64
    h8 a2[4];
#pragma unroll
    for (int c = 0; c < 4; c++)
        a2[c] = *(const h8*)(Hs + (r0 + cl) * LDK + quad * 8 + c * 32);

    f4 acc2[4];
#pragma unroll
    for (int t = 0; t < 4; t++) acc2[t] = (f4){0.f, 0.f, 0.f, 0.f};
    const h8* wv3 = (const h8*)w3s;
#pragma unroll
    for (int c = 0; c < 4; c++) {
#pragma unroll
        for (int t = 0; t < 4; t++)
            acc2[t] = __builtin_amdgcn_mfma_f32_16x16x32_f16(
                a2[c], wv3[(c * 4 + t) * 64 + lane], acc2[t], 0, 0, 0);
    }

    // epilogue 2: *dinv, store msg3
#pragma unroll
    for (int t = 0; t < 4; t++) {
        int c0 = t * 16 + cl;
#pragma unroll
        for (int r = 0; r < 4; r++) {
            int row = row0 + r0 + quad * 4 + r;
            if (row >= n) continue;
            float v = acc2[t][r] * dinv[row];
            C[(long)row * 64 + c0] = (_Float16)v;
        }
    }
}

extern "C" void kernel_launch(void* const* d_in, const int* in_sizes, int n_in,
                              void* d_out, int out_size, void* d_ws, size_t ws_size,
                              hipStream_t stream) {
    const float* x  = (const float*)d_in[0];
    const int*   ei = (const int*)d_in[1];
    const float* W1 = (const float*)d_in[2];
    const float* b1 = (const float*)d_in[3];
    const float* W2 = (const float*)d_in[4];
    const float* b2 = (const float*)d_in[5];
    const float* W3 = (const float*)d_in[6];
    const float* b3 = (const float*)d_in[7];
    float* out = (float*)d_out;

    const int N = in_sizes[0] / 64;
    const int E = in_sizes[1] / 2;
    const int* src = ei;
    const int* dst = ei + E;
    const int nbuck = (N + BNODES - 1) >> BSHIFT;   // 782
    const int chunk = (E + PB - 1) / PB;            // 6250
    const int n2 = PB * nbuck;                      // 200192
    const int nb2 = (n2 + 255) / 256;               // 782

    // workspace carve-up (4-byte elems)
    int*   hist   = (int*)d_ws;                   // PB*nbuck
    int*   offs   = hist + n2;                    // PB*nbuck
    int*   bsums  = offs + n2;                    // 1024
    int*   bbase  = bsums + 1024;                 // nbuck+1
    int*   rowst  = bbase + nbuck + 1;            // N
    int*   rowend = rowst + N;                    // N
    float* dinv   = (float*)(rowend + N);         // N
    int*   col    = (int*)(dinv + N);             // E
    _Float16* w1s = (_Float16*)(col + E);         // 64*128 f16
    _Float16* w2s = w1s + 64 * 128;               // 128*128 f16
    _Float16* w3s = w2s + 128 * 128;              // 128*64 f16
    float* P      = (float*)(w3s + 128 * 64);     // N*128 f32 worth
    float* Q      = P + (long)N * 128;            // N*128 f32 worth

    _Float16* msgX  = (_Float16*)P;   // N x 64 f16
    unsigned* ebuf  = (unsigned*)Q;   // E x 4B (dead after finalize)
    _Float16* msg1  = (_Float16*)Q;   // N x 128 f16 (F1 out)
    _Float16* aggH1 = (_Float16*)P;   // N x 128 f16 (msgX dead)
    _Float16* msg3  = (_Float16*)Q;   // N x 64 f16  (msg1 dead)

    const int gb = (N + 63) / 64;

    // ---- weight swizzle ----
    wprep3_k<<<16, 256, 0, stream>>>(W1, W2, W3, w1s, w2s, w3s);

    // ---- CSR build ----
    phist_k<<<PB, 256, 0, stream>>>(dst, hist, E, nbuck, chunk);
    scan_blocks_k<<<nb2, 256, 0, stream>>>(hist, offs, bsums, n2);
    mid_k<<<2, 1024, 0, stream>>>(bsums, nb2, hist, bbase, nbuck, E);
    part2_k<<<PB, 256, 0, stream>>>(src, dst, offs, bsums, ebuf, E, nbuck, chunk);
    finalize_k<<<nbuck, 256, 0, stream>>>(ebuf, hist, offs, bsums, bbase, nbuck,
                                          rowst, rowend, dinv, col, x, msgX, N);

    // ---- layer 1 (fused agg+gemm): msgX(P) -> msg1(Q) ----
    fag_k<64, 128, true, true, true><<<gb, 256, 0, stream>>>(
        msgX, rowst, rowend, col, dinv, w1s, b1, msg1, N);

    // ---- layer 2 gather: msg1(Q) -> aggH1(P) ----
    agg_f16_k<128, false, true><<<(N + 15) / 16, 256, 0, stream>>>(
        msg1, rowst, rowend, col, dinv, nullptr, (void*)aggH1, N);

    // ---- fused gemm2+gemm3: aggH1(P) -> msg3(Q) ----
    dgemm_k<<<gb, 256, 0, stream>>>(aggH1, w2s, w3s, b2, dinv, msg3, N);

    // ---- layer 3 gather: msg3(Q) -> out ----
    agg_f16_k<64, true, false><<<(N + 31) / 32, 256, 0, stream>>>(
        msg3, rowst, rowend, col, dinv, b3, (void*)out, N);
}